// Round 17
// baseline (59.248 us; speedup 1.0000x reference)
//
#include <hip/hip_runtime.h>

// Depthwise temporal FIR (FW=64, SAME pad low=31/high=32), weight-norm +
// positivity clamp + bias. out[t,c] = b[c] + sum_f relu(w[f,c]/||w||) x[t-31+f,c]
//
// Round-17: ACCUMULATOR-PERSISTENT, TAP-CHUNKED. R2-R16 lesson: any structure
// holding filter+window state (>~64 regs) gets its arrays parked by the
// allocator (~2x VALU inflation) no matter the occupancy hints. Inversion:
// hold only acc[16] (the outputs) and STREAM weights + x. Taps in 4 chunks
// of 16: per chunk load wf[16] (scaled), stream 31 x values, each feeding
// <=16 statically-indexed FMAs (triangular). Live set ~46 < 64 -> nothing to
// squeeze, 8 waves/SIMD. x re-read 4x and w re-read 2x come from L1/L2, not
// HBM (c-fast grid, R11). No LDS, no shuffles, no circular buffer.

#define T_DIM 4096
#define C_DIM 4096
#define PAD_L 31
#define R     16      // output rows per thread
#define CH    16      // taps per chunk
#define NCH   4       // chunks (NCH*CH == 64)

template <bool GUARD>
__device__ __forceinline__ void fir_body(const float* __restrict__ x,
                                         const float* __restrict__ w,
                                         const float* __restrict__ b,
                                         float* __restrict__ out,
                                         int c, int t0) {
    const float* __restrict__ xp = x + c;          // channel column base
    const float* __restrict__ wp = w + c;

    // ---- pass 1: ||w||^2 (values discarded; w is L2-resident, re-read later)
    float ss = 0.0f;
#pragma unroll
    for (int f = 0; f < 64; ++f) {
        const float v = wp[f * C_DIM];
        ss = fmaf(v, v, ss);
    }
    const float inv = 1.0f / fmaxf(sqrtf(ss), 1e-8f);

    // ---- persistent accumulators, seeded with bias ----
    const float bv = b[c];
    float acc[R];
#pragma unroll
    for (int r = 0; r < R; ++r) acc[r] = bv;

    // one streamed x value; j, r bounds compile-time -> static wf/acc indices
#define XSTEP(j)                                                              \
    {                                                                         \
        const int m = xb + (j);                                               \
        const float xv = (!GUARD || ((unsigned)m < (unsigned)T_DIM))          \
                             ? xp[(long long)m * C_DIM] : 0.0f;               \
        _Pragma("unroll")                                                     \
        for (int r = 0; r < R; ++r)                                           \
            if ((j) - r >= 0 && (j) - r < CH)   /* folds at compile time */   \
                acc[r] = fmaf(wf[(j) - r], xv, acc[r]);                       \
    }

    // ---- 4 tap-chunks; only acc[] persists across iterations ----
#pragma unroll 1
    for (int q = 0; q < NCH; ++q) {
        // chunk weights, scaled + clamped (16 regs, chunk-local live range)
        float wf[CH];
#pragma unroll
        for (int j = 0; j < CH; ++j)
            wf[j] = fmaxf(wp[(q * CH + j) * C_DIM] * inv, 0.0f);

        // x window for this chunk: x[xb .. xb+30]
        const int xb = t0 - PAD_L + q * CH;

        XSTEP(0)  XSTEP(1)  XSTEP(2)  XSTEP(3)  XSTEP(4)  XSTEP(5)
        XSTEP(6)  XSTEP(7)  XSTEP(8)  XSTEP(9)  XSTEP(10) XSTEP(11)
        XSTEP(12) XSTEP(13) XSTEP(14) XSTEP(15) XSTEP(16) XSTEP(17)
        XSTEP(18) XSTEP(19) XSTEP(20) XSTEP(21) XSTEP(22) XSTEP(23)
        XSTEP(24) XSTEP(25) XSTEP(26) XSTEP(27) XSTEP(28) XSTEP(29)
        XSTEP(30)
    }
#undef XSTEP

    // ---- coalesced nontemporal stores ----
    float* __restrict__ op = out + (long long)t0 * C_DIM + c;
#pragma unroll
    for (int r = 0; r < R; ++r)
        __builtin_nontemporal_store(acc[r], op + (long long)r * C_DIM);
}

__global__ __launch_bounds__(256)
void depthwise_fir_kernel(const float* __restrict__ x, const float* __restrict__ w,
                          const float* __restrict__ b, float* __restrict__ out) {
    const int c  = blockIdx.x * 256 + threadIdx.x;   // c-blocks fastest (R11)
    const int t0 = blockIdx.y * R;
    // zero-pad guard only where the 47-row window can leave [0, T):
    // t0-31 < 0  (blockIdx.y < 2)  or  t0+47 > 4095  (last 2 blocks)
    if (blockIdx.y < 2 || blockIdx.y >= gridDim.y - 2)
        fir_body<true>(x, w, b, out, c, t0);
    else
        fir_body<false>(x, w, b, out, c, t0);
}

extern "C" void kernel_launch(void* const* d_in, const int* in_sizes, int n_in,
                              void* d_out, int out_size, void* d_ws, size_t ws_size,
                              hipStream_t stream) {
    const float* x = (const float*)d_in[0];   // [T, C]
    const float* w = (const float*)d_in[1];   // [FW, C]
    const float* b = (const float*)d_in[2];   // [C]
    float* out = (float*)d_out;               // [T, C]

    dim3 grid(C_DIM / 256, T_DIM / R);        // 16 x 256 = 4096 blocks = 16/CU
    dim3 block(256);
    hipLaunchKernelGGL(depthwise_fir_kernel, grid, block, 0, stream, x, w, b, out);
}